// Round 15
// baseline (359.387 us; speedup 1.0000x reference)
//
#include <hip/hip_runtime.h>
#include <hip/hip_bf16.h>
#include <math.h>

constexpr int B_ = 16, C_ = 12, H_ = 128, W_ = 128, HID = 128;
constexpr float TAILF = 3.0f, MBWF = 0.001f, MBHF = 0.001f, MDF = 0.001f;

typedef __attribute__((ext_vector_type(8))) short bf16x8;
typedef __attribute__((ext_vector_type(4))) short bf16x4;
typedef __attribute__((ext_vector_type(4))) float f32x4;
typedef __attribute__((ext_vector_type(2))) float f32x2;

__device__ __forceinline__ short bf16bits(float v) {
    __hip_bfloat16 t = __float2bfloat16(v);
    return *reinterpret_cast<short*>(&t);
}
__device__ __forceinline__ float bf2f(short s) {
    __hip_bfloat16 t = *reinterpret_cast<__hip_bfloat16*>(&s);
    return __bfloat162float(t);
}
__device__ __forceinline__ float frcp(float x) {
    return __builtin_amdgcn_rcpf(x);
}
__device__ __forceinline__ float softplus_fast(float v) {
    return (v > 20.f) ? v : __logf(1.f + __expf(v));
}

// ==================== merged weight pack kernel ====================
// A-fragment layout: lane l, m-tile mt: oc = mt*16 + (l&15); k_local = (l>>4)*8 + j
__global__ void pack_all_kern(const float* __restrict__ w1,
                              const float* __restrict__ w2,
                              const float* __restrict__ w3,
                              __hip_bfloat16* __restrict__ wp1,
                              __hip_bfloat16* __restrict__ wp2,
                              __hip_bfloat16* __restrict__ wp3) {
    const int blk = blockIdx.x;
    if (blk < 80) {                               // w1: 5*8*64*8 = 20480
        int e = blk * 256 + threadIdx.x;
        int j = e & 7, lane = (e >> 3) & 63, mt = (e >> 9) & 7;
        int chunk = e >> 12;                      // 0..4
        int oc = mt * 16 + (lane & 15);
        int k_local = (lane >> 4) * 8 + j;        // 0..31
        int kpos = 2 * chunk + (k_local >> 4);    // 0..9 (9 invalid)
        int ic = k_local & 15;
        float v = (kpos < 9) ? w1[(oc * 16 + ic) * 9 + kpos] : 0.f;
        wp1[e] = __float2bfloat16(v);
    } else if (blk < 656) {                       // w2: 9*4*8*64*8 = 147456
        int e = (blk - 80) * 256 + threadIdx.x;
        int j = e & 7, lane = (e >> 3) & 63, mt = (e >> 9) & 7;
        int chunk = (e >> 12) & 3, kpos = e >> 14;
        int oc = mt * 16 + (lane & 15);
        int ic = chunk * 32 + (lane >> 4) * 8 + j;
        wp2[e] = __float2bfloat16(w2[(oc * 128 + ic) * 9 + kpos]);
    } else {                                      // w3: 9*4*24*64*8 = 442368
        int e = (blk - 656) * 256 + threadIdx.x;
        int j = e & 7, lane = (e >> 3) & 63;
        int rest = e >> 9;
        int mt = rest % 24; rest /= 24;
        int chunk = rest & 3, kpos = rest >> 2;
        int ocp = mt * 16 + (lane & 15);          // 0..383 (oc' = c*24 + jp)
        int c = ocp / 24, jp = ocp % 24;
        int ic = chunk * 32 + (lane >> 4) * 8 + j;
        float v = 0.f;
        if (ocp < 288 && jp < 23)
            v = w3[((c * 23 + jp) * 128 + ic) * 9 + kpos];
        wp3[e] = __float2bfloat16(v);
    }
}

// ==================== conv1: MFMA implicit GEMM ====================
__global__ __launch_bounds__(256) void conv1_mfma_kern(
    const float* __restrict__ x, const float* __restrict__ cond,
    const __hip_bfloat16* __restrict__ wp1,
    const float* __restrict__ b1,
    __hip_bfloat16* __restrict__ h1)
{
    const int tile = blockIdx.x & 255;
    const int b    = blockIdx.x >> 8;
    const int h0 = (tile >> 4) << 3;
    const int w0 = (tile & 15) << 3;
    const int tid = threadIdx.x;
    const int wv = tid >> 6, l = tid & 63;
    const int lg = l >> 4, ln = l & 15;

    __shared__ __hip_bfloat16 sB[100 * 20];   // [pos 10x10][ch pad 20]

    for (int e = tid; e < 1600; e += 256) {
        int ch = e / 100, pos = e % 100;
        int ph = pos / 10, pw = pos % 10;
        int gh = h0 + ph - 1, gw = w0 + pw - 1;
        float v = 0.f;
        if (gh >= 0 && gh < H_ && gw >= 0 && gw < W_) {
            if (ch < 12) {
                v = ((gh + gw) & 1) ? x[((b * C_ + ch) * H_ + gh) * W_ + gw] : 0.f;
            } else {
                v = cond[((b * 4 + (ch - 12)) * H_ + gh) * W_ + gw];
            }
        }
        sB[pos * 20 + ch] = __float2bfloat16(v);
    }
    __syncthreads();

    f32x4 acc[2][4];
#pragma unroll
    for (int mi = 0; mi < 2; ++mi) {
        const int ocbase = (wv * 2 + mi) * 16 + lg * 4;
#pragma unroll
        for (int nt = 0; nt < 4; ++nt)
#pragma unroll
            for (int r = 0; r < 4; ++r)
                acc[mi][nt][r] = b1[ocbase + r];
    }

#pragma unroll
    for (int chunk = 0; chunk < 5; ++chunk) {
        const int kpos = (chunk == 4) ? 8 : (2 * chunk + (lg >> 1));
        const int kh = kpos / 3, kw = kpos % 3;
        bf16x8 afr[2];
#pragma unroll
        for (int mi = 0; mi < 2; ++mi)
            afr[mi] = *reinterpret_cast<const bf16x8*>(
                &wp1[(size_t)((chunk * 8 + wv * 2 + mi) * 64 + l) * 8]);
        bf16x8 bfr[4];
#pragma unroll
        for (int nt = 0; nt < 4; ++nt) {
            int px = nt * 16 + ln;
            int pos = ((px >> 3) + kh) * 10 + (px & 7) + kw;
            bfr[nt] = *reinterpret_cast<const bf16x8*>(&sB[pos * 20 + (lg & 1) * 8]);
        }
#pragma unroll
        for (int mi = 0; mi < 2; ++mi)
#pragma unroll
            for (int nt = 0; nt < 4; ++nt)
                acc[mi][nt] = __builtin_amdgcn_mfma_f32_16x16x32_bf16(
                    afr[mi], bfr[nt], acc[mi][nt], 0, 0, 0);
    }

#pragma unroll
    for (int mi = 0; mi < 2; ++mi) {
#pragma unroll
        for (int nt = 0; nt < 4; ++nt) {
            int px = nt * 16 + ln;
            int h = h0 + (px >> 3), w = w0 + (px & 7);
            bf16x4 o;
#pragma unroll
            for (int r = 0; r < 4; ++r)
                o[r] = bf16bits(fmaxf(acc[mi][nt][r], 0.f));
            *reinterpret_cast<bf16x4*>(
                &h1[(size_t)((b * H_ + h) * W_ + w) * HID + (wv * 2 + mi) * 16 + lg * 4]) = o;
        }
    }
}

// ==================== conv2: MFMA, full-tile LDS (stage once, 2 barriers) ====================
// grid = B*256 tiles (8x8 px); 4 waves; wave: 2 octiles x 4 ntiles
// Full 128-ch tile staged once into 25.6KB; k-loop barrier-free.
// Layout: row64 = pos*2 + (g>>3); slot XOR-swizzled by (row&7).
__global__ __launch_bounds__(256) void conv2_mfma_kern(
    const __hip_bfloat16* __restrict__ h1,
    const __hip_bfloat16* __restrict__ wp2,
    const float* __restrict__ b2,
    __hip_bfloat16* __restrict__ h2)
{
    const int tile = blockIdx.x & 255;
    const int b    = blockIdx.x >> 8;
    const int h0 = (tile >> 4) << 3;
    const int w0 = (tile & 15) << 3;
    const int tid = threadIdx.x;
    const int wv = tid >> 6, l = tid & 63;
    const int lg = l >> 4, ln = l & 15;

    __shared__ __hip_bfloat16 sB[200 * 64];   // 25.6KB

    f32x4 acc[2][4];
#pragma unroll
    for (int mi = 0; mi < 2; ++mi) {
        const int ocbase = (wv * 2 + mi) * 16 + lg * 4;
#pragma unroll
        for (int nt = 0; nt < 4; ++nt)
#pragma unroll
            for (int r = 0; r < 4; ++r)
                acc[mi][nt][r] = b2[ocbase + r];
    }

    // stage entire tile (100 pos x 16 ch-groups)
    for (int s = tid; s < 1600; s += 256) {
        int pos = s >> 4, g = s & 15;
        int ph = pos / 10, pw = pos % 10;
        int gh = h0 + ph - 1, gw = w0 + pw - 1;
        bf16x8 v = {0, 0, 0, 0, 0, 0, 0, 0};
        if (gh >= 0 && gh < H_ && gw >= 0 && gw < W_)
            v = *reinterpret_cast<const bf16x8*>(
                &h1[(size_t)((b * H_ + gh) * W_ + gw) * HID + g * 8]);
        int row = pos * 2 + (g >> 3);
        *reinterpret_cast<bf16x8*>(&sB[row * 64 + 8 * ((g & 7) ^ (row & 7))]) = v;
    }
    __syncthreads();

    for (int chunk = 0; chunk < 4; ++chunk) {
#pragma unroll
        for (int kpos = 0; kpos < 9; ++kpos) {
            const int kh = kpos / 3, kw = kpos % 3;
            bf16x8 afr[2];
#pragma unroll
            for (int mi = 0; mi < 2; ++mi)
                afr[mi] = *reinterpret_cast<const bf16x8*>(
                    &wp2[(size_t)(((kpos * 4 + chunk) * 8 + wv * 2 + mi) * 64 + l) * 8]);
            bf16x8 bfr[4];
#pragma unroll
            for (int nt = 0; nt < 4; ++nt) {
                int px = nt * 16 + ln;
                int pos = ((px >> 3) + kh) * 10 + (px & 7) + kw;
                int row = pos * 2 + (chunk >> 1);
                int slot = (chunk & 1) * 4 + lg;
                bfr[nt] = *reinterpret_cast<const bf16x8*>(
                    &sB[row * 64 + 8 * (slot ^ (row & 7))]);
            }
#pragma unroll
            for (int mi = 0; mi < 2; ++mi)
#pragma unroll
                for (int nt = 0; nt < 4; ++nt)
                    acc[mi][nt] = __builtin_amdgcn_mfma_f32_16x16x32_bf16(
                        afr[mi], bfr[nt], acc[mi][nt], 0, 0, 0);
        }
    }
#pragma unroll
    for (int mi = 0; mi < 2; ++mi) {
#pragma unroll
        for (int nt = 0; nt < 4; ++nt) {
            int px = nt * 16 + ln;
            int h = h0 + (px >> 3), w = w0 + (px & 7);
            bf16x4 o;
#pragma unroll
            for (int r = 0; r < 4; ++r)
                o[r] = bf16bits(fmaxf(acc[mi][nt][r], 0.f));
            *reinterpret_cast<bf16x4*>(
                &h2[(size_t)((b * H_ + h) * W_ + w) * HID + (wv * 2 + mi) * 16 + lg * 4]) = o;
        }
    }
}

// ==================== conv3 param GEMM: chunk-pair staging (2 barrier pairs) ====================
// grid = 8 b-images * 128 tiles * 3 mblocks; tile = 16 rows x 8 cols = 64 active px.
// M' = 384 (oc' = c*24+jp layout, 288 real); wave = 2 mt x 4 nt.
// LDS: row = pos, 64 bf16/row (one chunk-pair's 64 ch), XOR slot swizzle. 23KB.
// Output: park bf16 [pxa 8*8192][oc' 288]
__global__ __launch_bounds__(256) void conv3_gemm_kern(
    const __hip_bfloat16* __restrict__ h2,
    const __hip_bfloat16* __restrict__ wp3,
    const float* __restrict__ b3,
    __hip_bfloat16* __restrict__ park, int bbase)
{
    const int mblock = blockIdx.x % 3;
    const int t2 = blockIdx.x / 3;
    const int tile = t2 & 127;
    const int b8 = t2 >> 7;
    const int b = bbase + b8;
    const int r0 = (tile >> 4) << 4;     // row strip *16
    const int w0 = (tile & 15) << 3;     // col strip *8
    const int tid = threadIdx.x;
    const int wv = tid >> 6, l = tid & 63;
    const int lg = l >> 4, ln = l & 15;

    __shared__ __hip_bfloat16 sB[180 * 64];   // [pos 18x10][64 bf16, swizzled] 23KB

    f32x4 acc[2][4];
#pragma unroll
    for (int mi = 0; mi < 2; ++mi) {
#pragma unroll
        for (int r = 0; r < 4; ++r) {
            int ocp = mblock * 128 + (wv * 2 + mi) * 16 + lg * 4 + r;
            int c = ocp / 24, jp = ocp % 24;
            float bv = (ocp < 288 && jp < 23) ? b3[c * 23 + jp] : 0.f;
#pragma unroll
            for (int nt = 0; nt < 4; ++nt) acc[mi][nt][r] = bv;
        }
    }

    for (int cp = 0; cp < 2; ++cp) {
        __syncthreads();
        // stage chunk-pair cp (64 channels): 180 pos x 8 groups
        for (int s = tid; s < 1440; s += 256) {
            int pos = s >> 3, g = s & 7;
            int ph = pos / 10, pw = pos % 10;
            int gh = r0 + ph - 1, gw = w0 + pw - 1;
            bf16x8 v = {0, 0, 0, 0, 0, 0, 0, 0};
            if (gh >= 0 && gh < H_ && gw >= 0 && gw < W_)
                v = *reinterpret_cast<const bf16x8*>(
                    &h2[(size_t)((b * H_ + gh) * W_ + gw) * HID + cp * 64 + g * 8]);
            *reinterpret_cast<bf16x8*>(&sB[pos * 64 + 8 * (g ^ (pos & 7))]) = v;
        }
        __syncthreads();
#pragma unroll
        for (int cc = 0; cc < 2; ++cc) {
            const int chunk = cp * 2 + cc;
#pragma unroll
            for (int kpos = 0; kpos < 9; ++kpos) {
                const int kh = kpos / 3, kw = kpos % 3;
                bf16x8 afr[2];
#pragma unroll
                for (int mi = 0; mi < 2; ++mi) {
                    int mtg = mblock * 8 + wv * 2 + mi;
                    afr[mi] = *reinterpret_cast<const bf16x8*>(
                        &wp3[(size_t)(((kpos * 4 + chunk) * 24 + mtg) * 64 + l) * 8]);
                }
                bf16x8 bfr[4];
#pragma unroll
                for (int nt = 0; nt < 4; ++nt) {
                    int px = nt * 16 + ln;
                    int rr = px >> 2, a = px & 3;
                    int pos = (rr + kh) * 10 + 2 * a + (rr & 1) + kw;
                    int slot = cc * 4 + lg;
                    bfr[nt] = *reinterpret_cast<const bf16x8*>(
                        &sB[pos * 64 + 8 * (slot ^ (pos & 7))]);
                }
#pragma unroll
                for (int mi = 0; mi < 2; ++mi)
#pragma unroll
                    for (int nt = 0; nt < 4; ++nt)
                        acc[mi][nt] = __builtin_amdgcn_mfma_f32_16x16x32_bf16(
                            afr[mi], bfr[nt], acc[mi][nt], 0, 0, 0);
            }
        }
    }

    // write params: park[(b8*8192 + gh*64 + whalf)*288 + oc']
#pragma unroll
    for (int mi = 0; mi < 2; ++mi) {
        const int ocb = mblock * 128 + (wv * 2 + mi) * 16 + lg * 4;
        if (ocb < 288) {
#pragma unroll
            for (int nt = 0; nt < 4; ++nt) {
                int px = nt * 16 + ln;
                int rr = px >> 2, a = px & 3;
                int gh = r0 + rr;
                int whalf = (w0 >> 1) + a;
                bf16x4 o;
#pragma unroll
                for (int r = 0; r < 4; ++r) o[r] = bf16bits(acc[mi][nt][r]);
                *reinterpret_cast<bf16x4*>(
                    &park[(size_t)(b8 * 8192 + gh * 64 + whalf) * 288 + ocb]) = o;
            }
        }
    }
}

// ==================== RQS spline (merged halves, fast-math) ====================
// grid = 6144 x 256; thread = (b, pxa, c) over all 16 images
__global__ __launch_bounds__(256) void rqs_kern(
    const float* __restrict__ x,
    const __hip_bfloat16* __restrict__ park0,
    const __hip_bfloat16* __restrict__ park1,
    float* __restrict__ out, float* __restrict__ ws_lad)
{
    const int tid = threadIdx.x;
    const int e = blockIdx.x * 256 + tid;
    const int c = e % 12;
    const int px_lin = e / 12;               // 0..131071
    const int b = px_lin >> 13;              // 0..15
    const int pxa = px_lin & 8191;
    const int px_half = px_lin & 65535;      // index within park half
    const __hip_bfloat16* park = (b < 8) ? park0 : park1;
    const int gh = pxa >> 6, colhalf = pxa & 63;
    const int par = gh & 1;                  // active col parity

    __shared__ float s_red[256];

    // load 24 params (23 real)
    const __hip_bfloat16* pr = &park[(size_t)px_half * 288 + c * 24];
    bf16x8 v0 = *reinterpret_cast<const bf16x8*>(pr);
    bf16x8 v1 = *reinterpret_cast<const bf16x8*>(pr + 8);
    bf16x8 v2 = *reinterpret_cast<const bf16x8*>(pr + 16);
    float p[23];
#pragma unroll
    for (int j = 0; j < 8; ++j) p[j] = bf2f(v0[j]);
#pragma unroll
    for (int j = 0; j < 8; ++j) p[8 + j] = bf2f(v1[j]);
#pragma unroll
    for (int j = 0; j < 7; ++j) p[16 + j] = bf2f(v2[j]);

    float mw = p[0];
#pragma unroll
    for (int j = 1; j < 8; ++j) mw = fmaxf(mw, p[j]);
    float ew[8], sw = 0.f;
#pragma unroll
    for (int j = 0; j < 8; ++j) { ew[j] = __expf(p[j] - mw); sw += ew[j]; }
    float mh = p[8];
#pragma unroll
    for (int j = 1; j < 8; ++j) mh = fmaxf(mh, p[8 + j]);
    float eh[8], sh = 0.f;
#pragma unroll
    for (int j = 0; j < 8; ++j) { eh[j] = __expf(p[8 + j] - mh); sh += eh[j]; }

    float cwv[9], chv[9];
    cwv[0] = -TAILF; chv[0] = -TAILF;
    float cum_w = 0.f, cum_h = 0.f;
    const float invsw = frcp(sw), invsh = frcp(sh);
#pragma unroll
    for (int j = 0; j < 8; ++j) {
        cum_w += MBWF + (1.f - MBWF * 8.f) * ew[j] * invsw;
        cum_h += MBHF + (1.f - MBHF * 8.f) * eh[j] * invsh;
        cwv[j + 1] = 2.f * TAILF * cum_w - TAILF;
        chv[j + 1] = 2.f * TAILF * cum_h - TAILF;
    }
    cwv[8] = TAILF; chv[8] = TAILF;

    float dv[9];
    dv[0] = 1.f; dv[8] = 1.f;
#pragma unroll
    for (int j = 1; j < 8; ++j) dv[j] = MDF + softplus_fast(p[15 + j]);

    const int base = ((b * C_ + c) * H_ + gh) * W_ + 2 * colhalf;
    f32x2 xp = *reinterpret_cast<const f32x2*>(&x[base]);
    const float xa = par ? xp[1] : xp[0];
    const float xf = par ? xp[0] : xp[1];

    const float xc = fminf(fmaxf(xa, -TAILF), TAILF);
    int cnt = 0;
#pragma unroll
    for (int i = 0; i < 9; ++i) cnt += (xc >= cwv[i]) ? 1 : 0;
    int idx = cnt - 1;
    idx = idx < 0 ? 0 : (idx > 7 ? 7 : idx);

    float icw = cwv[0], iwd = cwv[1] - cwv[0];
    float ich = chv[0], ihd = chv[1] - chv[0];
    float idl = dv[0], idr = dv[1];
#pragma unroll
    for (int i = 1; i < 8; ++i) {
        if (idx == i) {
            icw = cwv[i]; iwd = cwv[i + 1] - cwv[i];
            ich = chv[i]; ihd = chv[i + 1] - chv[i];
            idl = dv[i];  idr = dv[i + 1];
        }
    }
    const float inviwd = frcp(iwd);
    const float delta = ihd * inviwd;
    const float th  = (xc - icw) * inviwd;
    const float th1 = 1.f - th;
    const float num = ihd * (delta * th * th + idl * th * th1);
    const float den = delta + (idl + idr - 2.f * delta) * th * th1;
    float y = ich + num * frcp(den);
    const float dnum = delta * delta *
        (idr * th * th + 2.f * delta * th * th1 + idl * th1 * th1);
    float lad = __logf(dnum) - 2.f * __logf(den);
    const bool inside = (xa >= -TAILF) && (xa <= TAILF);
    y = inside ? y : xa;
    lad = inside ? lad : 0.f;

    f32x2 op;
    op[par] = y; op[par ^ 1] = xf;
    *reinterpret_cast<f32x2*>(&out[base]) = op;

    s_red[tid] = lad;
    __syncthreads();
    for (int s = 128; s > 0; s >>= 1) {
        if (tid < s) s_red[tid] += s_red[tid + s];
        __syncthreads();
    }
    if (tid == 0) ws_lad[blockIdx.x] = s_red[0];
}

// ==================== logdet final reduce ====================
// ws_lad: 6144 entries, 384 consecutive per image b
__global__ void logdet_reduce_kern(const float* __restrict__ ws_lad,
                                   const float* __restrict__ logdet_in,
                                   float* __restrict__ out)
{
    int b = threadIdx.x;
    if (b < B_) {
        float s = logdet_in[b];
        const float* p = &ws_lad[b * 384];
        for (int i = 0; i < 384; ++i) s += p[i];
        out[(size_t)B_ * C_ * H_ * W_ + b] = s;
    }
}

extern "C" void kernel_launch(void* const* d_in, const int* in_sizes, int n_in,
                              void* d_out, int out_size, void* d_ws, size_t ws_size,
                              hipStream_t stream) {
    const float* x    = (const float*)d_in[0];
    const float* ld   = (const float*)d_in[1];
    const float* cond = (const float*)d_in[2];
    const float* w1   = (const float*)d_in[3];
    const float* b1   = (const float*)d_in[4];
    const float* w2   = (const float*)d_in[5];
    const float* b2   = (const float*)d_in[6];
    const float* w3   = (const float*)d_in[7];
    const float* b3   = (const float*)d_in[8];
    float* out = (float*)d_out;

    // ws layout (128 MiB):
    //   h1 bf16 NHWC [0, 64MiB)              -- dead after conv2
    //   h2 bf16 NHWC [64MiB, 128MiB)         -- dead after conv3_gemm half1
    //   park half0 bf16 [0, 36MiB)           -- aliases h1 (dead)
    //   park half1 bf16 [36MiB, 72MiB)       -- tail overlaps h2 images 0-1 (dead by then)
    //   ws_lad (24KB) at 128MiB-32KB         -- beyond all live data at RQS time
    // d_out parking (dead once both GEMMs complete; RQS rewrites everything):
    //   wp2 at +0 (288KB); wp1 at +512KB (40KB); wp3 at +1MiB (884KB)
    const size_t NPIX = (size_t)B_ * H_ * W_;
    __hip_bfloat16* h1 = (__hip_bfloat16*)d_ws;
    __hip_bfloat16* h2 = h1 + NPIX * HID;
    const size_t PARK_HALF = (size_t)8 * 8192 * 288;      // elements
    __hip_bfloat16* park0 = (__hip_bfloat16*)d_ws;
    __hip_bfloat16* park1 = park0 + PARK_HALF;
    float* ws_lad = (float*)((char*)d_ws + (((size_t)128 << 20) - 32768));
    __hip_bfloat16* wp2 = (__hip_bfloat16*)d_out;
    __hip_bfloat16* wp1 = (__hip_bfloat16*)((char*)d_out + (1u << 19));
    __hip_bfloat16* wp3 = (__hip_bfloat16*)((char*)d_out + (1u << 20));

    hipLaunchKernelGGL(pack_all_kern, dim3(2384), dim3(256), 0, stream,
                       w1, w2, w3, wp1, wp2, wp3);
    hipLaunchKernelGGL(conv1_mfma_kern, dim3(16 * 256), dim3(256), 0, stream,
                       x, cond, wp1, b1, h1);
    hipLaunchKernelGGL(conv2_mfma_kern, dim3(16 * 256), dim3(256), 0, stream,
                       h1, wp2, b2, h2);
    hipLaunchKernelGGL(conv3_gemm_kern, dim3(8 * 128 * 3), dim3(256), 0, stream,
                       h2, wp3, b3, park0, 0);
    hipLaunchKernelGGL(conv3_gemm_kern, dim3(8 * 128 * 3), dim3(256), 0, stream,
                       h2, wp3, b3, park1, 8);
    hipLaunchKernelGGL(rqs_kern, dim3(6144), dim3(256), 0, stream,
                       x, park0, park1, out, ws_lad);
    hipLaunchKernelGGL(logdet_reduce_kern, dim3(1), dim3(64), 0, stream,
                       ws_lad, ld, out);
}

// Round 16
// 291.561 us; speedup vs baseline: 1.2326x; 1.2326x over previous
//
#include <hip/hip_runtime.h>
#include <hip/hip_bf16.h>
#include <math.h>

constexpr int B_ = 16, C_ = 12, H_ = 128, W_ = 128, HID = 128;
constexpr float TAILF = 3.0f, MBWF = 0.001f, MBHF = 0.001f, MDF = 0.001f;

typedef __attribute__((ext_vector_type(8))) short bf16x8;
typedef __attribute__((ext_vector_type(4))) short bf16x4;
typedef __attribute__((ext_vector_type(4))) float f32x4;
typedef __attribute__((ext_vector_type(2))) float f32x2;

__device__ __forceinline__ short bf16bits(float v) {
    __hip_bfloat16 t = __float2bfloat16(v);
    return *reinterpret_cast<short*>(&t);
}
__device__ __forceinline__ float bf2f(short s) {
    __hip_bfloat16 t = *reinterpret_cast<__hip_bfloat16*>(&s);
    return __bfloat162float(t);
}
__device__ __forceinline__ float frcp(float x) {
    return __builtin_amdgcn_rcpf(x);
}
__device__ __forceinline__ float softplus_fast(float v) {
    return (v > 20.f) ? v : __logf(1.f + __expf(v));
}

// ==================== merged weight pack kernel ====================
// A-fragment layout: lane l, m-tile mt: oc = mt*16 + (l&15); k_local = (l>>4)*8 + j
__global__ void pack_all_kern(const float* __restrict__ w1,
                              const float* __restrict__ w2,
                              const float* __restrict__ w3,
                              __hip_bfloat16* __restrict__ wp1,
                              __hip_bfloat16* __restrict__ wp2,
                              __hip_bfloat16* __restrict__ wp3) {
    const int blk = blockIdx.x;
    if (blk < 80) {                               // w1: 5*8*64*8 = 20480
        int e = blk * 256 + threadIdx.x;
        int j = e & 7, lane = (e >> 3) & 63, mt = (e >> 9) & 7;
        int chunk = e >> 12;                      // 0..4
        int oc = mt * 16 + (lane & 15);
        int k_local = (lane >> 4) * 8 + j;        // 0..31
        int kpos = 2 * chunk + (k_local >> 4);    // 0..9 (9 invalid)
        int ic = k_local & 15;
        float v = (kpos < 9) ? w1[(oc * 16 + ic) * 9 + kpos] : 0.f;
        wp1[e] = __float2bfloat16(v);
    } else if (blk < 656) {                       // w2: 9*4*8*64*8 = 147456
        int e = (blk - 80) * 256 + threadIdx.x;
        int j = e & 7, lane = (e >> 3) & 63, mt = (e >> 9) & 7;
        int chunk = (e >> 12) & 3, kpos = e >> 14;
        int oc = mt * 16 + (lane & 15);
        int ic = chunk * 32 + (lane >> 4) * 8 + j;
        wp2[e] = __float2bfloat16(w2[(oc * 128 + ic) * 9 + kpos]);
    } else {                                      // w3: 9*4*24*64*8 = 442368
        int e = (blk - 656) * 256 + threadIdx.x;
        int j = e & 7, lane = (e >> 3) & 63;
        int rest = e >> 9;
        int mt = rest % 24; rest /= 24;
        int chunk = rest & 3, kpos = rest >> 2;
        int ocp = mt * 16 + (lane & 15);          // 0..383 (oc' = c*24 + jp)
        int c = ocp / 24, jp = ocp % 24;
        int ic = chunk * 32 + (lane >> 4) * 8 + j;
        float v = 0.f;
        if (ocp < 288 && jp < 23)
            v = w3[((c * 23 + jp) * 128 + ic) * 9 + kpos];
        wp3[e] = __float2bfloat16(v);
    }
}

// ==================== conv1: MFMA implicit GEMM ====================
__global__ __launch_bounds__(256) void conv1_mfma_kern(
    const float* __restrict__ x, const float* __restrict__ cond,
    const __hip_bfloat16* __restrict__ wp1,
    const float* __restrict__ b1,
    __hip_bfloat16* __restrict__ h1)
{
    const int tile = blockIdx.x & 255;
    const int b    = blockIdx.x >> 8;
    const int h0 = (tile >> 4) << 3;
    const int w0 = (tile & 15) << 3;
    const int tid = threadIdx.x;
    const int wv = tid >> 6, l = tid & 63;
    const int lg = l >> 4, ln = l & 15;

    __shared__ __hip_bfloat16 sB[100 * 20];   // [pos 10x10][ch pad 20]

    for (int e = tid; e < 1600; e += 256) {
        int ch = e / 100, pos = e % 100;
        int ph = pos / 10, pw = pos % 10;
        int gh = h0 + ph - 1, gw = w0 + pw - 1;
        float v = 0.f;
        if (gh >= 0 && gh < H_ && gw >= 0 && gw < W_) {
            if (ch < 12) {
                v = ((gh + gw) & 1) ? x[((b * C_ + ch) * H_ + gh) * W_ + gw] : 0.f;
            } else {
                v = cond[((b * 4 + (ch - 12)) * H_ + gh) * W_ + gw];
            }
        }
        sB[pos * 20 + ch] = __float2bfloat16(v);
    }
    __syncthreads();

    f32x4 acc[2][4];
#pragma unroll
    for (int mi = 0; mi < 2; ++mi) {
        const int ocbase = (wv * 2 + mi) * 16 + lg * 4;
#pragma unroll
        for (int nt = 0; nt < 4; ++nt)
#pragma unroll
            for (int r = 0; r < 4; ++r)
                acc[mi][nt][r] = b1[ocbase + r];
    }

#pragma unroll
    for (int chunk = 0; chunk < 5; ++chunk) {
        const int kpos = (chunk == 4) ? 8 : (2 * chunk + (lg >> 1));
        const int kh = kpos / 3, kw = kpos % 3;
        bf16x8 afr[2];
#pragma unroll
        for (int mi = 0; mi < 2; ++mi)
            afr[mi] = *reinterpret_cast<const bf16x8*>(
                &wp1[(size_t)((chunk * 8 + wv * 2 + mi) * 64 + l) * 8]);
        bf16x8 bfr[4];
#pragma unroll
        for (int nt = 0; nt < 4; ++nt) {
            int px = nt * 16 + ln;
            int pos = ((px >> 3) + kh) * 10 + (px & 7) + kw;
            bfr[nt] = *reinterpret_cast<const bf16x8*>(&sB[pos * 20 + (lg & 1) * 8]);
        }
#pragma unroll
        for (int mi = 0; mi < 2; ++mi)
#pragma unroll
            for (int nt = 0; nt < 4; ++nt)
                acc[mi][nt] = __builtin_amdgcn_mfma_f32_16x16x32_bf16(
                    afr[mi], bfr[nt], acc[mi][nt], 0, 0, 0);
    }

#pragma unroll
    for (int mi = 0; mi < 2; ++mi) {
#pragma unroll
        for (int nt = 0; nt < 4; ++nt) {
            int px = nt * 16 + ln;
            int h = h0 + (px >> 3), w = w0 + (px & 7);
            bf16x4 o;
#pragma unroll
            for (int r = 0; r < 4; ++r)
                o[r] = bf16bits(fmaxf(acc[mi][nt][r], 0.f));
            *reinterpret_cast<bf16x4*>(
                &h1[(size_t)((b * H_ + h) * W_ + w) * HID + (wv * 2 + mi) * 16 + lg * 4]) = o;
        }
    }
}

// ==================== conv2: MFMA, full-tile LDS (stage once, 2 barriers) ====================
// grid = B*256 tiles (8x8 px); 4 waves; wave: 2 octiles x 4 ntiles
// Full 128-ch tile staged once into 25.6KB; k-loop barrier-free.
// Layout: row64 = pos*2 + (g>>3); slot XOR-swizzled by (row&7).
__global__ __launch_bounds__(256) void conv2_mfma_kern(
    const __hip_bfloat16* __restrict__ h1,
    const __hip_bfloat16* __restrict__ wp2,
    const float* __restrict__ b2,
    __hip_bfloat16* __restrict__ h2)
{
    const int tile = blockIdx.x & 255;
    const int b    = blockIdx.x >> 8;
    const int h0 = (tile >> 4) << 3;
    const int w0 = (tile & 15) << 3;
    const int tid = threadIdx.x;
    const int wv = tid >> 6, l = tid & 63;
    const int lg = l >> 4, ln = l & 15;

    __shared__ __hip_bfloat16 sB[200 * 64];   // 25.6KB

    f32x4 acc[2][4];
#pragma unroll
    for (int mi = 0; mi < 2; ++mi) {
        const int ocbase = (wv * 2 + mi) * 16 + lg * 4;
#pragma unroll
        for (int nt = 0; nt < 4; ++nt)
#pragma unroll
            for (int r = 0; r < 4; ++r)
                acc[mi][nt][r] = b2[ocbase + r];
    }

    // stage entire tile (100 pos x 16 ch-groups)
    for (int s = tid; s < 1600; s += 256) {
        int pos = s >> 4, g = s & 15;
        int ph = pos / 10, pw = pos % 10;
        int gh = h0 + ph - 1, gw = w0 + pw - 1;
        bf16x8 v = {0, 0, 0, 0, 0, 0, 0, 0};
        if (gh >= 0 && gh < H_ && gw >= 0 && gw < W_)
            v = *reinterpret_cast<const bf16x8*>(
                &h1[(size_t)((b * H_ + gh) * W_ + gw) * HID + g * 8]);
        int row = pos * 2 + (g >> 3);
        *reinterpret_cast<bf16x8*>(&sB[row * 64 + 8 * ((g & 7) ^ (row & 7))]) = v;
    }
    __syncthreads();

    for (int chunk = 0; chunk < 4; ++chunk) {
#pragma unroll
        for (int kpos = 0; kpos < 9; ++kpos) {
            const int kh = kpos / 3, kw = kpos % 3;
            bf16x8 afr[2];
#pragma unroll
            for (int mi = 0; mi < 2; ++mi)
                afr[mi] = *reinterpret_cast<const bf16x8*>(
                    &wp2[(size_t)(((kpos * 4 + chunk) * 8 + wv * 2 + mi) * 64 + l) * 8]);
            bf16x8 bfr[4];
#pragma unroll
            for (int nt = 0; nt < 4; ++nt) {
                int px = nt * 16 + ln;
                int pos = ((px >> 3) + kh) * 10 + (px & 7) + kw;
                int row = pos * 2 + (chunk >> 1);
                int slot = (chunk & 1) * 4 + lg;
                bfr[nt] = *reinterpret_cast<const bf16x8*>(
                    &sB[row * 64 + 8 * (slot ^ (row & 7))]);
            }
#pragma unroll
            for (int mi = 0; mi < 2; ++mi)
#pragma unroll
                for (int nt = 0; nt < 4; ++nt)
                    acc[mi][nt] = __builtin_amdgcn_mfma_f32_16x16x32_bf16(
                        afr[mi], bfr[nt], acc[mi][nt], 0, 0, 0);
        }
    }
#pragma unroll
    for (int mi = 0; mi < 2; ++mi) {
#pragma unroll
        for (int nt = 0; nt < 4; ++nt) {
            int px = nt * 16 + ln;
            int h = h0 + (px >> 3), w = w0 + (px & 7);
            bf16x4 o;
#pragma unroll
            for (int r = 0; r < 4; ++r)
                o[r] = bf16bits(fmaxf(acc[mi][nt][r], 0.f));
            *reinterpret_cast<bf16x4*>(
                &h2[(size_t)((b * H_ + h) * W_ + w) * HID + (wv * 2 + mi) * 16 + lg * 4]) = o;
        }
    }
}

// ==================== conv3 param GEMM + T2 XOR-swizzled LDS (round-14 proven form) ====================
// grid = 8 b-images * 128 tiles * 3 mblocks; tile = 16 rows x 8 cols = 64 active px.
// M' = 384 (oc' = c*24+jp layout, 288 real); wave = 2 mt x 4 nt.
// Output: park bf16 [pxa 8*8192][oc' 288]
__global__ __launch_bounds__(256) void conv3_gemm_kern(
    const __hip_bfloat16* __restrict__ h2,
    const __hip_bfloat16* __restrict__ wp3,
    const float* __restrict__ b3,
    __hip_bfloat16* __restrict__ park, int bbase)
{
    const int mblock = blockIdx.x % 3;
    const int t2 = blockIdx.x / 3;
    const int tile = t2 & 127;
    const int b8 = t2 >> 7;
    const int b = bbase + b8;
    const int r0 = (tile >> 4) << 4;     // row strip *16
    const int w0 = (tile & 15) << 3;     // col strip *8
    const int tid = threadIdx.x;
    const int wv = tid >> 6, l = tid & 63;
    const int lg = l >> 4, ln = l & 15;

    __shared__ __hip_bfloat16 sB[180 * 64];   // [pos 18x10][64 bf16 row, swizzled] 22.5KB

    f32x4 acc[2][4];
#pragma unroll
    for (int mi = 0; mi < 2; ++mi) {
#pragma unroll
        for (int r = 0; r < 4; ++r) {
            int ocp = mblock * 128 + (wv * 2 + mi) * 16 + lg * 4 + r;
            int c = ocp / 24, jp = ocp % 24;
            float bv = (ocp < 288 && jp < 23) ? b3[c * 23 + jp] : 0.f;
#pragma unroll
            for (int nt = 0; nt < 4; ++nt) acc[mi][nt][r] = bv;
        }
    }

    for (int chunk = 0; chunk < 4; ++chunk) {
        __syncthreads();
        for (int s = tid; s < 720; s += 256) {
            int pos = s >> 2, g = s & 3;          // 180 pos x 4 groups
            int ph = pos / 10, pw = pos % 10;
            int gh = r0 + ph - 1, gw = w0 + pw - 1;
            bf16x8 v = {0, 0, 0, 0, 0, 0, 0, 0};
            if (gh >= 0 && gh < H_ && gw >= 0 && gw < W_)
                v = *reinterpret_cast<const bf16x8*>(
                    &h2[(size_t)((b * H_ + gh) * W_ + gw) * HID + chunk * 32 + g * 8]);
            *reinterpret_cast<bf16x8*>(&sB[pos * 64 + 8 * (g ^ (pos & 7))]) = v;
        }
        __syncthreads();
#pragma unroll
        for (int kpos = 0; kpos < 9; ++kpos) {
            const int kh = kpos / 3, kw = kpos % 3;
            bf16x8 afr[2];
#pragma unroll
            for (int mi = 0; mi < 2; ++mi) {
                int mtg = mblock * 8 + wv * 2 + mi;
                afr[mi] = *reinterpret_cast<const bf16x8*>(
                    &wp3[(size_t)(((kpos * 4 + chunk) * 24 + mtg) * 64 + l) * 8]);
            }
            bf16x8 bfr[4];
#pragma unroll
            for (int nt = 0; nt < 4; ++nt) {
                int px = nt * 16 + ln;
                int rr = px >> 2, a = px & 3;
                int pos = (rr + kh) * 10 + 2 * a + (rr & 1) + kw;
                bfr[nt] = *reinterpret_cast<const bf16x8*>(
                    &sB[pos * 64 + 8 * (lg ^ (pos & 7))]);
            }
#pragma unroll
            for (int mi = 0; mi < 2; ++mi)
#pragma unroll
                for (int nt = 0; nt < 4; ++nt)
                    acc[mi][nt] = __builtin_amdgcn_mfma_f32_16x16x32_bf16(
                        afr[mi], bfr[nt], acc[mi][nt], 0, 0, 0);
        }
    }

    // write params: park[(b8*8192 + gh*64 + whalf)*288 + oc']
#pragma unroll
    for (int mi = 0; mi < 2; ++mi) {
        const int ocb = mblock * 128 + (wv * 2 + mi) * 16 + lg * 4;
        if (ocb < 288) {
#pragma unroll
            for (int nt = 0; nt < 4; ++nt) {
                int px = nt * 16 + ln;
                int rr = px >> 2, a = px & 3;
                int gh = r0 + rr;
                int whalf = (w0 >> 1) + a;
                bf16x4 o;
#pragma unroll
                for (int r = 0; r < 4; ++r) o[r] = bf16bits(acc[mi][nt][r]);
                *reinterpret_cast<bf16x4*>(
                    &park[(size_t)(b8 * 8192 + gh * 64 + whalf) * 288 + ocb]) = o;
            }
        }
    }
}

// ==================== RQS spline (merged halves, fast-math) ====================
// grid = 6144 x 256; thread = (b, pxa, c) over all 16 images
__global__ __launch_bounds__(256) void rqs_kern(
    const float* __restrict__ x,
    const __hip_bfloat16* __restrict__ park0,
    const __hip_bfloat16* __restrict__ park1,
    float* __restrict__ out, float* __restrict__ ws_lad)
{
    const int tid = threadIdx.x;
    const int e = blockIdx.x * 256 + tid;
    const int c = e % 12;
    const int px_lin = e / 12;               // 0..131071
    const int b = px_lin >> 13;              // 0..15
    const int pxa = px_lin & 8191;
    const int px_half = px_lin & 65535;      // index within park half
    const __hip_bfloat16* park = (b < 8) ? park0 : park1;
    const int gh = pxa >> 6, colhalf = pxa & 63;
    const int par = gh & 1;                  // active col parity

    __shared__ float s_red[256];

    // load 24 params (23 real)
    const __hip_bfloat16* pr = &park[(size_t)px_half * 288 + c * 24];
    bf16x8 v0 = *reinterpret_cast<const bf16x8*>(pr);
    bf16x8 v1 = *reinterpret_cast<const bf16x8*>(pr + 8);
    bf16x8 v2 = *reinterpret_cast<const bf16x8*>(pr + 16);
    float p[23];
#pragma unroll
    for (int j = 0; j < 8; ++j) p[j] = bf2f(v0[j]);
#pragma unroll
    for (int j = 0; j < 8; ++j) p[8 + j] = bf2f(v1[j]);
#pragma unroll
    for (int j = 0; j < 7; ++j) p[16 + j] = bf2f(v2[j]);

    float mw = p[0];
#pragma unroll
    for (int j = 1; j < 8; ++j) mw = fmaxf(mw, p[j]);
    float ew[8], sw = 0.f;
#pragma unroll
    for (int j = 0; j < 8; ++j) { ew[j] = __expf(p[j] - mw); sw += ew[j]; }
    float mh = p[8];
#pragma unroll
    for (int j = 1; j < 8; ++j) mh = fmaxf(mh, p[8 + j]);
    float eh[8], sh = 0.f;
#pragma unroll
    for (int j = 0; j < 8; ++j) { eh[j] = __expf(p[8 + j] - mh); sh += eh[j]; }

    float cwv[9], chv[9];
    cwv[0] = -TAILF; chv[0] = -TAILF;
    float cum_w = 0.f, cum_h = 0.f;
    const float invsw = frcp(sw), invsh = frcp(sh);
#pragma unroll
    for (int j = 0; j < 8; ++j) {
        cum_w += MBWF + (1.f - MBWF * 8.f) * ew[j] * invsw;
        cum_h += MBHF + (1.f - MBHF * 8.f) * eh[j] * invsh;
        cwv[j + 1] = 2.f * TAILF * cum_w - TAILF;
        chv[j + 1] = 2.f * TAILF * cum_h - TAILF;
    }
    cwv[8] = TAILF; chv[8] = TAILF;

    float dv[9];
    dv[0] = 1.f; dv[8] = 1.f;
#pragma unroll
    for (int j = 1; j < 8; ++j) dv[j] = MDF + softplus_fast(p[15 + j]);

    const int base = ((b * C_ + c) * H_ + gh) * W_ + 2 * colhalf;
    f32x2 xp = *reinterpret_cast<const f32x2*>(&x[base]);
    const float xa = par ? xp[1] : xp[0];
    const float xf = par ? xp[0] : xp[1];

    const float xc = fminf(fmaxf(xa, -TAILF), TAILF);
    int cnt = 0;
#pragma unroll
    for (int i = 0; i < 9; ++i) cnt += (xc >= cwv[i]) ? 1 : 0;
    int idx = cnt - 1;
    idx = idx < 0 ? 0 : (idx > 7 ? 7 : idx);

    float icw = cwv[0], iwd = cwv[1] - cwv[0];
    float ich = chv[0], ihd = chv[1] - chv[0];
    float idl = dv[0], idr = dv[1];
#pragma unroll
    for (int i = 1; i < 8; ++i) {
        if (idx == i) {
            icw = cwv[i]; iwd = cwv[i + 1] - cwv[i];
            ich = chv[i]; ihd = chv[i + 1] - chv[i];
            idl = dv[i];  idr = dv[i + 1];
        }
    }
    const float inviwd = frcp(iwd);
    const float delta = ihd * inviwd;
    const float th  = (xc - icw) * inviwd;
    const float th1 = 1.f - th;
    const float num = ihd * (delta * th * th + idl * th * th1);
    const float den = delta + (idl + idr - 2.f * delta) * th * th1;
    float y = ich + num * frcp(den);
    const float dnum = delta * delta *
        (idr * th * th + 2.f * delta * th * th1 + idl * th1 * th1);
    float lad = __logf(dnum) - 2.f * __logf(den);
    const bool inside = (xa >= -TAILF) && (xa <= TAILF);
    y = inside ? y : xa;
    lad = inside ? lad : 0.f;

    f32x2 op;
    op[par] = y; op[par ^ 1] = xf;
    *reinterpret_cast<f32x2*>(&out[base]) = op;

    s_red[tid] = lad;
    __syncthreads();
    for (int s = 128; s > 0; s >>= 1) {
        if (tid < s) s_red[tid] += s_red[tid + s];
        __syncthreads();
    }
    if (tid == 0) ws_lad[blockIdx.x] = s_red[0];
}

// ==================== logdet final reduce ====================
// ws_lad: 6144 entries, 384 consecutive per image b
__global__ void logdet_reduce_kern(const float* __restrict__ ws_lad,
                                   const float* __restrict__ logdet_in,
                                   float* __restrict__ out)
{
    int b = threadIdx.x;
    if (b < B_) {
        float s = logdet_in[b];
        const float* p = &ws_lad[b * 384];
        for (int i = 0; i < 384; ++i) s += p[i];
        out[(size_t)B_ * C_ * H_ * W_ + b] = s;
    }
}

extern "C" void kernel_launch(void* const* d_in, const int* in_sizes, int n_in,
                              void* d_out, int out_size, void* d_ws, size_t ws_size,
                              hipStream_t stream) {
    const float* x    = (const float*)d_in[0];
    const float* ld   = (const float*)d_in[1];
    const float* cond = (const float*)d_in[2];
    const float* w1   = (const float*)d_in[3];
    const float* b1   = (const float*)d_in[4];
    const float* w2   = (const float*)d_in[5];
    const float* b2   = (const float*)d_in[6];
    const float* w3   = (const float*)d_in[7];
    const float* b3   = (const float*)d_in[8];
    float* out = (float*)d_out;

    // ws layout (128 MiB):
    //   h1 bf16 NHWC [0, 64MiB)              -- dead after conv2
    //   h2 bf16 NHWC [64MiB, 128MiB)         -- dead after conv3_gemm half1
    //   park half0 bf16 [0, 36MiB)           -- aliases h1 (dead)
    //   park half1 bf16 [36MiB, 72MiB)       -- tail overlaps h2 images 0-1 (dead by then)
    //   ws_lad (24KB) at 128MiB-32KB         -- beyond all live data at RQS time
    // d_out parking (dead once both GEMMs complete; RQS rewrites everything):
    //   wp2 at +0 (288KB); wp1 at +512KB (40KB); wp3 at +1MiB (884KB)
    const size_t NPIX = (size_t)B_ * H_ * W_;
    __hip_bfloat16* h1 = (__hip_bfloat16*)d_ws;
    __hip_bfloat16* h2 = h1 + NPIX * HID;
    const size_t PARK_HALF = (size_t)8 * 8192 * 288;      // elements
    __hip_bfloat16* park0 = (__hip_bfloat16*)d_ws;
    __hip_bfloat16* park1 = park0 + PARK_HALF;
    float* ws_lad = (float*)((char*)d_ws + (((size_t)128 << 20) - 32768));
    __hip_bfloat16* wp2 = (__hip_bfloat16*)d_out;
    __hip_bfloat16* wp1 = (__hip_bfloat16*)((char*)d_out + (1u << 19));
    __hip_bfloat16* wp3 = (__hip_bfloat16*)((char*)d_out + (1u << 20));

    hipLaunchKernelGGL(pack_all_kern, dim3(2384), dim3(256), 0, stream,
                       w1, w2, w3, wp1, wp2, wp3);
    hipLaunchKernelGGL(conv1_mfma_kern, dim3(16 * 256), dim3(256), 0, stream,
                       x, cond, wp1, b1, h1);
    hipLaunchKernelGGL(conv2_mfma_kern, dim3(16 * 256), dim3(256), 0, stream,
                       h1, wp2, b2, h2);
    hipLaunchKernelGGL(conv3_gemm_kern, dim3(8 * 128 * 3), dim3(256), 0, stream,
                       h2, wp3, b3, park0, 0);
    hipLaunchKernelGGL(conv3_gemm_kern, dim3(8 * 128 * 3), dim3(256), 0, stream,
                       h2, wp3, b3, park1, 8);
    hipLaunchKernelGGL(rqs_kern, dim3(6144), dim3(256), 0, stream,
                       x, park0, park1, out, ws_lad);
    hipLaunchKernelGGL(logdet_reduce_kern, dim3(1), dim3(64), 0, stream,
                       ws_lad, ld, out);
}

// Round 17
// 280.763 us; speedup vs baseline: 1.2800x; 1.0385x over previous
//
#include <hip/hip_runtime.h>
#include <hip/hip_bf16.h>
#include <math.h>

constexpr int B_ = 16, C_ = 12, H_ = 128, W_ = 128, HID = 128;
constexpr float TAILF = 3.0f, MBWF = 0.001f, MBHF = 0.001f, MDF = 0.001f;

typedef __attribute__((ext_vector_type(8))) short bf16x8;
typedef __attribute__((ext_vector_type(4))) short bf16x4;
typedef __attribute__((ext_vector_type(4))) float f32x4;
typedef __attribute__((ext_vector_type(2))) float f32x2;

__device__ __forceinline__ short bf16bits(float v) {
    __hip_bfloat16 t = __float2bfloat16(v);
    return *reinterpret_cast<short*>(&t);
}
__device__ __forceinline__ float bf2f(short s) {
    __hip_bfloat16 t = *reinterpret_cast<__hip_bfloat16*>(&s);
    return __bfloat162float(t);
}
__device__ __forceinline__ float frcp(float x) {
    return __builtin_amdgcn_rcpf(x);
}
__device__ __forceinline__ float softplus_fast(float v) {
    return (v > 20.f) ? v : __logf(1.f + __expf(v));
}

// ==================== merged weight pack kernel ====================
// A-fragment layout: lane l, m-tile mt: oc = mt*16 + (l&15); k_local = (l>>4)*8 + j
__global__ void pack_all_kern(const float* __restrict__ w1,
                              const float* __restrict__ w2,
                              const float* __restrict__ w3,
                              __hip_bfloat16* __restrict__ wp1,
                              __hip_bfloat16* __restrict__ wp2,
                              __hip_bfloat16* __restrict__ wp3) {
    const int blk = blockIdx.x;
    if (blk < 80) {                               // w1: 5*8*64*8 = 20480
        int e = blk * 256 + threadIdx.x;
        int j = e & 7, lane = (e >> 3) & 63, mt = (e >> 9) & 7;
        int chunk = e >> 12;                      // 0..4
        int oc = mt * 16 + (lane & 15);
        int k_local = (lane >> 4) * 8 + j;        // 0..31
        int kpos = 2 * chunk + (k_local >> 4);    // 0..9 (9 invalid)
        int ic = k_local & 15;
        float v = (kpos < 9) ? w1[(oc * 16 + ic) * 9 + kpos] : 0.f;
        wp1[e] = __float2bfloat16(v);
    } else if (blk < 656) {                       // w2: 9*4*8*64*8 = 147456
        int e = (blk - 80) * 256 + threadIdx.x;
        int j = e & 7, lane = (e >> 3) & 63, mt = (e >> 9) & 7;
        int chunk = (e >> 12) & 3, kpos = e >> 14;
        int oc = mt * 16 + (lane & 15);
        int ic = chunk * 32 + (lane >> 4) * 8 + j;
        wp2[e] = __float2bfloat16(w2[(oc * 128 + ic) * 9 + kpos]);
    } else {                                      // w3: 9*4*24*64*8 = 442368
        int e = (blk - 656) * 256 + threadIdx.x;
        int j = e & 7, lane = (e >> 3) & 63;
        int rest = e >> 9;
        int mt = rest % 24; rest /= 24;
        int chunk = rest & 3, kpos = rest >> 2;
        int ocp = mt * 16 + (lane & 15);          // 0..383 (oc' = c*24 + jp)
        int c = ocp / 24, jp = ocp % 24;
        int ic = chunk * 32 + (lane >> 4) * 8 + j;
        float v = 0.f;
        if (ocp < 288 && jp < 23)
            v = w3[((c * 23 + jp) * 128 + ic) * 9 + kpos];
        wp3[e] = __float2bfloat16(v);
    }
}

// ==================== conv1: MFMA implicit GEMM ====================
__global__ __launch_bounds__(256) void conv1_mfma_kern(
    const float* __restrict__ x, const float* __restrict__ cond,
    const __hip_bfloat16* __restrict__ wp1,
    const float* __restrict__ b1,
    __hip_bfloat16* __restrict__ h1)
{
    const int tile = blockIdx.x & 255;
    const int b    = blockIdx.x >> 8;
    const int h0 = (tile >> 4) << 3;
    const int w0 = (tile & 15) << 3;
    const int tid = threadIdx.x;
    const int wv = tid >> 6, l = tid & 63;
    const int lg = l >> 4, ln = l & 15;

    __shared__ __hip_bfloat16 sB[100 * 20];   // [pos 10x10][ch pad 20]

    for (int e = tid; e < 1600; e += 256) {
        int ch = e / 100, pos = e % 100;
        int ph = pos / 10, pw = pos % 10;
        int gh = h0 + ph - 1, gw = w0 + pw - 1;
        float v = 0.f;
        if (gh >= 0 && gh < H_ && gw >= 0 && gw < W_) {
            if (ch < 12) {
                v = ((gh + gw) & 1) ? x[((b * C_ + ch) * H_ + gh) * W_ + gw] : 0.f;
            } else {
                v = cond[((b * 4 + (ch - 12)) * H_ + gh) * W_ + gw];
            }
        }
        sB[pos * 20 + ch] = __float2bfloat16(v);
    }
    __syncthreads();

    f32x4 acc[2][4];
#pragma unroll
    for (int mi = 0; mi < 2; ++mi) {
        const int ocbase = (wv * 2 + mi) * 16 + lg * 4;
#pragma unroll
        for (int nt = 0; nt < 4; ++nt)
#pragma unroll
            for (int r = 0; r < 4; ++r)
                acc[mi][nt][r] = b1[ocbase + r];
    }

#pragma unroll
    for (int chunk = 0; chunk < 5; ++chunk) {
        const int kpos = (chunk == 4) ? 8 : (2 * chunk + (lg >> 1));
        const int kh = kpos / 3, kw = kpos % 3;
        bf16x8 afr[2];
#pragma unroll
        for (int mi = 0; mi < 2; ++mi)
            afr[mi] = *reinterpret_cast<const bf16x8*>(
                &wp1[(size_t)((chunk * 8 + wv * 2 + mi) * 64 + l) * 8]);
        bf16x8 bfr[4];
#pragma unroll
        for (int nt = 0; nt < 4; ++nt) {
            int px = nt * 16 + ln;
            int pos = ((px >> 3) + kh) * 10 + (px & 7) + kw;
            bfr[nt] = *reinterpret_cast<const bf16x8*>(&sB[pos * 20 + (lg & 1) * 8]);
        }
#pragma unroll
        for (int mi = 0; mi < 2; ++mi)
#pragma unroll
            for (int nt = 0; nt < 4; ++nt)
                acc[mi][nt] = __builtin_amdgcn_mfma_f32_16x16x32_bf16(
                    afr[mi], bfr[nt], acc[mi][nt], 0, 0, 0);
    }

#pragma unroll
    for (int mi = 0; mi < 2; ++mi) {
#pragma unroll
        for (int nt = 0; nt < 4; ++nt) {
            int px = nt * 16 + ln;
            int h = h0 + (px >> 3), w = w0 + (px & 7);
            bf16x4 o;
#pragma unroll
            for (int r = 0; r < 4; ++r)
                o[r] = bf16bits(fmaxf(acc[mi][nt][r], 0.f));
            *reinterpret_cast<bf16x4*>(
                &h1[(size_t)((b * H_ + h) * W_ + w) * HID + (wv * 2 + mi) * 16 + lg * 4]) = o;
        }
    }
}

// ==================== conv2: MFMA implicit GEMM + T2 XOR-swizzled LDS ====================
// grid = B*256 tiles (8x8 px); 4 waves; wave: 2 octiles x 4 ntiles
// sB row = 64 bf16 (128B = XOR span); 16B slot swizzled by (pos&7).
__global__ __launch_bounds__(256) void conv2_mfma_kern(
    const __hip_bfloat16* __restrict__ h1,
    const __hip_bfloat16* __restrict__ wp2,
    const float* __restrict__ b2,
    __hip_bfloat16* __restrict__ h2)
{
    const int tile = blockIdx.x & 255;
    const int b    = blockIdx.x >> 8;
    const int h0 = (tile >> 4) << 3;
    const int w0 = (tile & 15) << 3;
    const int tid = threadIdx.x;
    const int wv = tid >> 6, l = tid & 63;
    const int lg = l >> 4, ln = l & 15;

    __shared__ __hip_bfloat16 sB[100 * 64];   // [pos 10x10][64 bf16 row, swizzled]

    f32x4 acc[2][4];
#pragma unroll
    for (int mi = 0; mi < 2; ++mi) {
        const int ocbase = (wv * 2 + mi) * 16 + lg * 4;
#pragma unroll
        for (int nt = 0; nt < 4; ++nt)
#pragma unroll
            for (int r = 0; r < 4; ++r)
                acc[mi][nt][r] = b2[ocbase + r];
    }

    for (int chunk = 0; chunk < 4; ++chunk) {
        __syncthreads();
        for (int s = tid; s < 400; s += 256) {
            int pos = s >> 2, g = s & 3;
            int ph = pos / 10, pw = pos % 10;
            int gh = h0 + ph - 1, gw = w0 + pw - 1;
            bf16x8 v = {0, 0, 0, 0, 0, 0, 0, 0};
            if (gh >= 0 && gh < H_ && gw >= 0 && gw < W_)
                v = *reinterpret_cast<const bf16x8*>(
                    &h1[(size_t)((b * H_ + gh) * W_ + gw) * HID + chunk * 32 + g * 8]);
            *reinterpret_cast<bf16x8*>(&sB[pos * 64 + 8 * (g ^ (pos & 7))]) = v;
        }
        __syncthreads();
#pragma unroll
        for (int kpos = 0; kpos < 9; ++kpos) {
            const int kh = kpos / 3, kw = kpos % 3;
            bf16x8 afr[2];
#pragma unroll
            for (int mi = 0; mi < 2; ++mi)
                afr[mi] = *reinterpret_cast<const bf16x8*>(
                    &wp2[(size_t)(((kpos * 4 + chunk) * 8 + wv * 2 + mi) * 64 + l) * 8]);
            bf16x8 bfr[4];
#pragma unroll
            for (int nt = 0; nt < 4; ++nt) {
                int px = nt * 16 + ln;
                int pos = ((px >> 3) + kh) * 10 + (px & 7) + kw;
                bfr[nt] = *reinterpret_cast<const bf16x8*>(
                    &sB[pos * 64 + 8 * (lg ^ (pos & 7))]);
            }
#pragma unroll
            for (int mi = 0; mi < 2; ++mi)
#pragma unroll
                for (int nt = 0; nt < 4; ++nt)
                    acc[mi][nt] = __builtin_amdgcn_mfma_f32_16x16x32_bf16(
                        afr[mi], bfr[nt], acc[mi][nt], 0, 0, 0);
        }
    }
#pragma unroll
    for (int mi = 0; mi < 2; ++mi) {
#pragma unroll
        for (int nt = 0; nt < 4; ++nt) {
            int px = nt * 16 + ln;
            int h = h0 + (px >> 3), w = w0 + (px & 7);
            bf16x4 o;
#pragma unroll
            for (int r = 0; r < 4; ++r)
                o[r] = bf16bits(fmaxf(acc[mi][nt][r], 0.f));
            *reinterpret_cast<bf16x4*>(
                &h2[(size_t)((b * H_ + h) * W_ + w) * HID + (wv * 2 + mi) * 16 + lg * 4]) = o;
        }
    }
}

// ==================== conv3 param GEMM + T2 XOR-swizzled LDS ====================
// grid = 8 b-images * 128 tiles * 3 mblocks; tile = 16 rows x 8 cols = 64 active px.
// M' = 384 (oc' = c*24+jp layout, 288 real); wave = 2 mt x 4 nt.
// Output: park bf16 [pxa 8*8192][oc' 288]
__global__ __launch_bounds__(256) void conv3_gemm_kern(
    const __hip_bfloat16* __restrict__ h2,
    const __hip_bfloat16* __restrict__ wp3,
    const float* __restrict__ b3,
    __hip_bfloat16* __restrict__ park, int bbase)
{
    const int mblock = blockIdx.x % 3;
    const int t2 = blockIdx.x / 3;
    const int tile = t2 & 127;
    const int b8 = t2 >> 7;
    const int b = bbase + b8;
    const int r0 = (tile >> 4) << 4;     // row strip *16
    const int w0 = (tile & 15) << 3;     // col strip *8
    const int tid = threadIdx.x;
    const int wv = tid >> 6, l = tid & 63;
    const int lg = l >> 4, ln = l & 15;

    __shared__ __hip_bfloat16 sB[180 * 64];   // [pos 18x10][64 bf16 row, swizzled] 22.5KB

    f32x4 acc[2][4];
#pragma unroll
    for (int mi = 0; mi < 2; ++mi) {
#pragma unroll
        for (int r = 0; r < 4; ++r) {
            int ocp = mblock * 128 + (wv * 2 + mi) * 16 + lg * 4 + r;
            int c = ocp / 24, jp = ocp % 24;
            float bv = (ocp < 288 && jp < 23) ? b3[c * 23 + jp] : 0.f;
#pragma unroll
            for (int nt = 0; nt < 4; ++nt) acc[mi][nt][r] = bv;
        }
    }

    for (int chunk = 0; chunk < 4; ++chunk) {
        __syncthreads();
        for (int s = tid; s < 720; s += 256) {
            int pos = s >> 2, g = s & 3;          // 180 pos x 4 groups
            int ph = pos / 10, pw = pos % 10;
            int gh = r0 + ph - 1, gw = w0 + pw - 1;
            bf16x8 v = {0, 0, 0, 0, 0, 0, 0, 0};
            if (gh >= 0 && gh < H_ && gw >= 0 && gw < W_)
                v = *reinterpret_cast<const bf16x8*>(
                    &h2[(size_t)((b * H_ + gh) * W_ + gw) * HID + chunk * 32 + g * 8]);
            *reinterpret_cast<bf16x8*>(&sB[pos * 64 + 8 * (g ^ (pos & 7))]) = v;
        }
        __syncthreads();
#pragma unroll
        for (int kpos = 0; kpos < 9; ++kpos) {
            const int kh = kpos / 3, kw = kpos % 3;
            bf16x8 afr[2];
#pragma unroll
            for (int mi = 0; mi < 2; ++mi) {
                int mtg = mblock * 8 + wv * 2 + mi;
                afr[mi] = *reinterpret_cast<const bf16x8*>(
                    &wp3[(size_t)(((kpos * 4 + chunk) * 24 + mtg) * 64 + l) * 8]);
            }
            bf16x8 bfr[4];
#pragma unroll
            for (int nt = 0; nt < 4; ++nt) {
                int px = nt * 16 + ln;
                int rr = px >> 2, a = px & 3;
                int pos = (rr + kh) * 10 + 2 * a + (rr & 1) + kw;
                bfr[nt] = *reinterpret_cast<const bf16x8*>(
                    &sB[pos * 64 + 8 * (lg ^ (pos & 7))]);
            }
#pragma unroll
            for (int mi = 0; mi < 2; ++mi)
#pragma unroll
                for (int nt = 0; nt < 4; ++nt)
                    acc[mi][nt] = __builtin_amdgcn_mfma_f32_16x16x32_bf16(
                        afr[mi], bfr[nt], acc[mi][nt], 0, 0, 0);
        }
    }

    // write params: park[(b8*8192 + gh*64 + whalf)*288 + oc']
#pragma unroll
    for (int mi = 0; mi < 2; ++mi) {
        const int ocb = mblock * 128 + (wv * 2 + mi) * 16 + lg * 4;
        if (ocb < 288) {
#pragma unroll
            for (int nt = 0; nt < 4; ++nt) {
                int px = nt * 16 + ln;
                int rr = px >> 2, a = px & 3;
                int gh = r0 + rr;
                int whalf = (w0 >> 1) + a;
                bf16x4 o;
#pragma unroll
                for (int r = 0; r < 4; ++r) o[r] = bf16bits(acc[mi][nt][r]);
                *reinterpret_cast<bf16x4*>(
                    &park[(size_t)(b8 * 8192 + gh * 64 + whalf) * 288 + ocb]) = o;
            }
        }
    }
}

// ==================== RQS spline (merged halves, fast-math) ====================
// grid = 6144 x 256; thread = (b, pxa, c) over all 16 images
__global__ __launch_bounds__(256) void rqs_kern(
    const float* __restrict__ x,
    const __hip_bfloat16* __restrict__ park0,
    const __hip_bfloat16* __restrict__ park1,
    float* __restrict__ out, float* __restrict__ ws_lad)
{
    const int tid = threadIdx.x;
    const int e = blockIdx.x * 256 + tid;
    const int c = e % 12;
    const int px_lin = e / 12;               // 0..131071
    const int b = px_lin >> 13;              // 0..15
    const int pxa = px_lin & 8191;
    const int px_half = px_lin & 65535;      // index within park half
    const __hip_bfloat16* park = (b < 8) ? park0 : park1;
    const int gh = pxa >> 6, colhalf = pxa & 63;
    const int par = gh & 1;                  // active col parity

    __shared__ float s_red[256];

    // load 24 params (23 real)
    const __hip_bfloat16* pr = &park[(size_t)px_half * 288 + c * 24];
    bf16x8 v0 = *reinterpret_cast<const bf16x8*>(pr);
    bf16x8 v1 = *reinterpret_cast<const bf16x8*>(pr + 8);
    bf16x8 v2 = *reinterpret_cast<const bf16x8*>(pr + 16);
    float p[23];
#pragma unroll
    for (int j = 0; j < 8; ++j) p[j] = bf2f(v0[j]);
#pragma unroll
    for (int j = 0; j < 8; ++j) p[8 + j] = bf2f(v1[j]);
#pragma unroll
    for (int j = 0; j < 7; ++j) p[16 + j] = bf2f(v2[j]);

    float mw = p[0];
#pragma unroll
    for (int j = 1; j < 8; ++j) mw = fmaxf(mw, p[j]);
    float ew[8], sw = 0.f;
#pragma unroll
    for (int j = 0; j < 8; ++j) { ew[j] = __expf(p[j] - mw); sw += ew[j]; }
    float mh = p[8];
#pragma unroll
    for (int j = 1; j < 8; ++j) mh = fmaxf(mh, p[8 + j]);
    float eh[8], sh = 0.f;
#pragma unroll
    for (int j = 0; j < 8; ++j) { eh[j] = __expf(p[8 + j] - mh); sh += eh[j]; }

    float cwv[9], chv[9];
    cwv[0] = -TAILF; chv[0] = -TAILF;
    float cum_w = 0.f, cum_h = 0.f;
    const float invsw = frcp(sw), invsh = frcp(sh);
#pragma unroll
    for (int j = 0; j < 8; ++j) {
        cum_w += MBWF + (1.f - MBWF * 8.f) * ew[j] * invsw;
        cum_h += MBHF + (1.f - MBHF * 8.f) * eh[j] * invsh;
        cwv[j + 1] = 2.f * TAILF * cum_w - TAILF;
        chv[j + 1] = 2.f * TAILF * cum_h - TAILF;
    }
    cwv[8] = TAILF; chv[8] = TAILF;

    float dv[9];
    dv[0] = 1.f; dv[8] = 1.f;
#pragma unroll
    for (int j = 1; j < 8; ++j) dv[j] = MDF + softplus_fast(p[15 + j]);

    const int base = ((b * C_ + c) * H_ + gh) * W_ + 2 * colhalf;
    f32x2 xp = *reinterpret_cast<const f32x2*>(&x[base]);
    const float xa = par ? xp[1] : xp[0];
    const float xf = par ? xp[0] : xp[1];

    const float xc = fminf(fmaxf(xa, -TAILF), TAILF);
    int cnt = 0;
#pragma unroll
    for (int i = 0; i < 9; ++i) cnt += (xc >= cwv[i]) ? 1 : 0;
    int idx = cnt - 1;
    idx = idx < 0 ? 0 : (idx > 7 ? 7 : idx);

    float icw = cwv[0], iwd = cwv[1] - cwv[0];
    float ich = chv[0], ihd = chv[1] - chv[0];
    float idl = dv[0], idr = dv[1];
#pragma unroll
    for (int i = 1; i < 8; ++i) {
        if (idx == i) {
            icw = cwv[i]; iwd = cwv[i + 1] - cwv[i];
            ich = chv[i]; ihd = chv[i + 1] - chv[i];
            idl = dv[i];  idr = dv[i + 1];
        }
    }
    const float inviwd = frcp(iwd);
    const float delta = ihd * inviwd;
    const float th  = (xc - icw) * inviwd;
    const float th1 = 1.f - th;
    const float num = ihd * (delta * th * th + idl * th * th1);
    const float den = delta + (idl + idr - 2.f * delta) * th * th1;
    float y = ich + num * frcp(den);
    const float dnum = delta * delta *
        (idr * th * th + 2.f * delta * th * th1 + idl * th1 * th1);
    float lad = __logf(dnum) - 2.f * __logf(den);
    const bool inside = (xa >= -TAILF) && (xa <= TAILF);
    y = inside ? y : xa;
    lad = inside ? lad : 0.f;

    f32x2 op;
    op[par] = y; op[par ^ 1] = xf;
    *reinterpret_cast<f32x2*>(&out[base]) = op;

    s_red[tid] = lad;
    __syncthreads();
    for (int s = 128; s > 0; s >>= 1) {
        if (tid < s) s_red[tid] += s_red[tid + s];
        __syncthreads();
    }
    if (tid == 0) ws_lad[blockIdx.x] = s_red[0];
}

// ==================== logdet final reduce ====================
// ws_lad: 6144 entries, 384 consecutive per image b
__global__ void logdet_reduce_kern(const float* __restrict__ ws_lad,
                                   const float* __restrict__ logdet_in,
                                   float* __restrict__ out)
{
    int b = threadIdx.x;
    if (b < B_) {
        float s = logdet_in[b];
        const float* p = &ws_lad[b * 384];
        for (int i = 0; i < 384; ++i) s += p[i];
        out[(size_t)B_ * C_ * H_ * W_ + b] = s;
    }
}

extern "C" void kernel_launch(void* const* d_in, const int* in_sizes, int n_in,
                              void* d_out, int out_size, void* d_ws, size_t ws_size,
                              hipStream_t stream) {
    const float* x    = (const float*)d_in[0];
    const float* ld   = (const float*)d_in[1];
    const float* cond = (const float*)d_in[2];
    const float* w1   = (const float*)d_in[3];
    const float* b1   = (const float*)d_in[4];
    const float* w2   = (const float*)d_in[5];
    const float* b2   = (const float*)d_in[6];
    const float* w3   = (const float*)d_in[7];
    const float* b3   = (const float*)d_in[8];
    float* out = (float*)d_out;

    // ws layout (128 MiB):
    //   h1 bf16 NHWC [0, 64MiB)              -- dead after conv2
    //   h2 bf16 NHWC [64MiB, 128MiB)         -- dead after conv3_gemm half1
    //   park half0 bf16 [0, 36MiB)           -- aliases h1 (dead)
    //   park half1 bf16 [36MiB, 72MiB)       -- tail overlaps h2 images 0-1 (dead by then)
    //   ws_lad (24KB) at 128MiB-32KB         -- beyond all live data at RQS time
    // d_out parking (dead once both GEMMs complete; RQS rewrites everything):
    //   wp2 at +0 (288KB); wp1 at +512KB (40KB); wp3 at +1MiB (884KB)
    const size_t NPIX = (size_t)B_ * H_ * W_;
    __hip_bfloat16* h1 = (__hip_bfloat16*)d_ws;
    __hip_bfloat16* h2 = h1 + NPIX * HID;
    const size_t PARK_HALF = (size_t)8 * 8192 * 288;      // elements
    __hip_bfloat16* park0 = (__hip_bfloat16*)d_ws;
    __hip_bfloat16* park1 = park0 + PARK_HALF;
    float* ws_lad = (float*)((char*)d_ws + (((size_t)128 << 20) - 32768));
    __hip_bfloat16* wp2 = (__hip_bfloat16*)d_out;
    __hip_bfloat16* wp1 = (__hip_bfloat16*)((char*)d_out + (1u << 19));
    __hip_bfloat16* wp3 = (__hip_bfloat16*)((char*)d_out + (1u << 20));

    hipLaunchKernelGGL(pack_all_kern, dim3(2384), dim3(256), 0, stream,
                       w1, w2, w3, wp1, wp2, wp3);
    hipLaunchKernelGGL(conv1_mfma_kern, dim3(16 * 256), dim3(256), 0, stream,
                       x, cond, wp1, b1, h1);
    hipLaunchKernelGGL(conv2_mfma_kern, dim3(16 * 256), dim3(256), 0, stream,
                       h1, wp2, b2, h2);
    hipLaunchKernelGGL(conv3_gemm_kern, dim3(8 * 128 * 3), dim3(256), 0, stream,
                       h2, wp3, b3, park0, 0);
    hipLaunchKernelGGL(conv3_gemm_kern, dim3(8 * 128 * 3), dim3(256), 0, stream,
                       h2, wp3, b3, park1, 8);
    hipLaunchKernelGGL(rqs_kern, dim3(6144), dim3(256), 0, stream,
                       x, park0, park1, out, ws_lad);
    hipLaunchKernelGGL(logdet_reduce_kern, dim3(1), dim3(64), 0, stream,
                       ws_lad, ld, out);
}